// Round 1
// baseline (1264.778 us; speedup 1.0000x reference)
//
#include <hip/hip_runtime.h>
#include <cstdint>

#define N 8192
#define NWORDS 128  // N/64
typedef unsigned long long u64;

// ---------------------------------------------------------------------------
// K1: build sort keys (descending score, stable by ascending index) + init aux
// ---------------------------------------------------------------------------
__global__ __launch_bounds__(256) void k_init(const float* __restrict__ scores,
                                              u64* __restrict__ keys,
                                              int* __restrict__ rank,
                                              int* __restrict__ cnt,
                                              float* __restrict__ prob,
                                              unsigned* __restrict__ y2m,
                                              int* __restrict__ first) {
  int i = blockIdx.x * 256 + threadIdx.x;
  if (i >= N) return;
  float sc = scores[i];
  // positive floats: bit pattern is order-preserving. Tie-break: smaller index
  // first under DESCENDING key sort -> use ~i in low bits.
  keys[i] = ((u64)__float_as_uint(sc) << 32) | (unsigned)(0xFFFFFFFFu - (unsigned)i);
  rank[i] = 0;
  cnt[i] = 0;
  prob[i] = 0.0f;
  y2m[i] = 0u;      // by2 > 0 always, so 0 is a safe identity for float-bits max
  first[i] = N;
}

// ---------------------------------------------------------------------------
// K2: rank by counting (rank[i] = #{j : key[j] > key[i]}) -> stable descending
// grid (32, 8): x = element block of 256, y = key chunk of 1024 (LDS-staged)
// ---------------------------------------------------------------------------
__global__ __launch_bounds__(256) void k_rank(const u64* __restrict__ keys,
                                              int* __restrict__ rank) {
  __shared__ u64 tile[1024];
  int e = blockIdx.x * 256 + threadIdx.x;
  int j0 = blockIdx.y * 1024;
  for (int t = threadIdx.x; t < 1024; t += 256) tile[t] = keys[j0 + t];
  __syncthreads();
  u64 ke = keys[e];
  int c = 0;
#pragma unroll 8
  for (int k = 0; k < 1024; ++k) c += (tile[k] > ke) ? 1 : 0;
  atomicAdd(&rank[e], c);
}

// ---------------------------------------------------------------------------
// K3: scatter into sorted SoA (clipped coords, score, area)
// ---------------------------------------------------------------------------
__global__ __launch_bounds__(256) void k_scatter(const float* __restrict__ boxes,
                                                 const float* __restrict__ scores,
                                                 const int* __restrict__ rank,
                                                 float* __restrict__ bx1s, float* __restrict__ by1s,
                                                 float* __restrict__ bx2s, float* __restrict__ by2s,
                                                 float* __restrict__ ss, float* __restrict__ areas) {
#pragma clang fp contract(off)
  int i = blockIdx.x * 256 + threadIdx.x;
  if (i >= N) return;
  int r = rank[i];
  float x1 = fminf(fmaxf(boxes[i * 4 + 0], 0.0f), 1920.0f);
  float y1 = fminf(fmaxf(boxes[i * 4 + 1], 0.0f), 1080.0f);
  float x2 = fminf(fmaxf(boxes[i * 4 + 2], 0.0f), 1920.0f);
  float y2 = fminf(fmaxf(boxes[i * 4 + 3], 0.0f), 1080.0f);
  bx1s[r] = x1; by1s[r] = y1; bx2s[r] = x2; by2s[r] = y2;
  ss[r] = scores[i];
  areas[r] = (x2 - x1 + 1.0f) * (y2 - y1 + 1.0f);
}

// ---------------------------------------------------------------------------
// K4: adjacency bitmask. Block (64 thr) computes a 64x64 tile:
// thread = one row i, 64 cols staged in LDS. mask[i*128 + bx] = 64 bits.
// fp contract OFF so iou matches the numpy reference bit-for-bit.
// ---------------------------------------------------------------------------
__global__ __launch_bounds__(64) void k_adj(const float* __restrict__ bx1s, const float* __restrict__ by1s,
                                            const float* __restrict__ bx2s, const float* __restrict__ by2s,
                                            const float* __restrict__ areas,
                                            u64* __restrict__ mask) {
#pragma clang fp contract(off)
  __shared__ float jx1[64], jy1[64], jx2[64], jy2[64], ja[64];
  int l = threadIdx.x;
  int j = blockIdx.x * 64 + l;
  jx1[l] = bx1s[j]; jy1[l] = by1s[j]; jx2[l] = bx2s[j]; jy2[l] = by2s[j]; ja[l] = areas[j];
  __syncthreads();
  int i = blockIdx.y * 64 + l;
  float x1 = bx1s[i], y1 = by1s[i], x2 = bx2s[i], y2 = by2s[i], ai = areas[i];
  u64 bits = 0;
#pragma unroll 4
  for (int jj = 0; jj < 64; ++jj) {
    float ix1 = fmaxf(x1, jx1[jj]);
    float iy1 = fmaxf(y1, jy1[jj]);
    float ix2 = fminf(x2, jx2[jj]);
    float iy2 = fminf(y2, jy2[jj]);
    float iw = fmaxf(ix2 - ix1 + 1.0f, 0.0f);
    float ih = fmaxf(iy2 - iy1 + 1.0f, 0.0f);
    float inter = iw * ih;
    float uni = (ai + ja[jj]) - inter;
    float iou = inter / uni;
    bits |= ((u64)(iou > 0.5f)) << jj;
  }
  mask[(size_t)i * NWORDS + blockIdx.x] = bits;
}

// ---------------------------------------------------------------------------
// K5: exact sequential greedy clustering. ONE wave, wave-synchronous.
// Lane l holds removed-mask words 2l,2l+1 (cols [128l, 128l+128)).
// Rows streamed in order with a 32-row register pipeline (ulong2 per lane/row).
// ---------------------------------------------------------------------------
__global__ __launch_bounds__(64) void k_scan(const ulong2* __restrict__ mask2,
                                             int* __restrict__ cluster) {
  const int l = threadIdx.x;
  u64 remv0 = 0, remv1 = 0;
  const int cb = l * 128;

  auto process = [&](ulong2 row, int i) {
    int wi = i >> 6;                                   // word holding bit i (uniform)
    u64 sel = (wi & 1) ? remv1 : remv0;                // each lane offers its slot
    u64 bw = __shfl(sel, wi >> 1);                     // word wi lives in lane wi>>1
    if (!((bw >> (i & 63)) & 1ull)) {                  // i unclaimed -> head (uniform)
      u64 r0 = row.x, r1 = row.y;
      u64 n0 = r0 & ~remv0, n1 = r1 & ~remv1;          // newly claimed by head i
      remv0 |= r0; remv1 |= r1;
      while (n0) { int t = __builtin_ctzll(n0); n0 &= n0 - 1; cluster[cb + t] = i; }
      while (n1) { int t = __builtin_ctzll(n1); n1 &= n1 - 1; cluster[cb + 64 + t] = i; }
    }
  };

  ulong2 A[16], B[16];
#pragma unroll
  for (int g = 0; g < 16; ++g) A[g] = mask2[(size_t)g * 64 + l];

  for (int base = 0; base < N; base += 32) {
#pragma unroll
    for (int g = 0; g < 16; ++g) B[g] = mask2[(size_t)(base + 16 + g) * 64 + l];
#pragma unroll
    for (int g = 0; g < 16; ++g) process(A[g], base + g);
    if (base + 32 < N) {
#pragma unroll
      for (int g = 0; g < 16; ++g) A[g] = mask2[(size_t)(base + 32 + g) * 64 + l];
    }
#pragma unroll
    for (int g = 0; g < 16; ++g) process(B[g], base + 16 + g);
  }
}

// ---------------------------------------------------------------------------
// K6: per-cluster count / prob-sum / max-y2 (atomics; float-max via uint bits)
// ---------------------------------------------------------------------------
__global__ __launch_bounds__(256) void k_seg(const int* __restrict__ cluster,
                                             const float* __restrict__ ss,
                                             const float* __restrict__ by2s,
                                             int* __restrict__ cnt,
                                             float* __restrict__ prob,
                                             unsigned* __restrict__ y2m) {
  int j = blockIdx.x * 256 + threadIdx.x;
  if (j >= N) return;
  int c = cluster[j];
  atomicAdd(&cnt[c], 1);
  atomicAdd(&prob[c], ss[j]);
  atomicMax(&y2m[c], __float_as_uint(by2s[j]));  // by2 > 0: bit order == float order
}

// ---------------------------------------------------------------------------
// K7: first index achieving the cluster max y2
// ---------------------------------------------------------------------------
__global__ __launch_bounds__(256) void k_first(const int* __restrict__ cluster,
                                               const float* __restrict__ by2s,
                                               const unsigned* __restrict__ y2m,
                                               int* __restrict__ first) {
  int j = blockIdx.x * 256 + threadIdx.x;
  if (j >= N) return;
  int c = cluster[j];
  if (by2s[j] >= __uint_as_float(y2m[c])) atomicMin(&first[c], j);
}

// ---------------------------------------------------------------------------
// K8: outputs. out[j][0..4] then keep[j] appended (floats 0/1).
// ---------------------------------------------------------------------------
__global__ __launch_bounds__(256) void k_out(const int* __restrict__ cluster,
                                             const float* __restrict__ bx1s, const float* __restrict__ by1s,
                                             const float* __restrict__ bx2s, const float* __restrict__ by2s,
                                             const int* __restrict__ cnt,
                                             const float* __restrict__ prob,
                                             const int* __restrict__ first,
                                             const int* __restrict__ num_models,
                                             float* __restrict__ out) {
  int j = blockIdx.x * 256 + threadIdx.x;
  if (j >= N) return;
  int c = cluster[j];
  int nm = num_models[0];
  bool valid = (float)cnt[c] >= (float)nm / 3.0f;   // counts integer -> boundary safe
  bool pick = (first[c] == j);
  bool keep = pick && valid;
  float o0 = 0.f, o1 = 0.f, o2 = 0.f, o3 = 0.f, o4 = 0.f;
  if (keep) {
    o0 = bx1s[j]; o1 = by1s[j]; o2 = bx2s[j]; o3 = by2s[j];
    o4 = prob[c] / (float)nm;
  }
  out[j * 5 + 0] = o0;
  out[j * 5 + 1] = o1;
  out[j * 5 + 2] = o2;
  out[j * 5 + 3] = o3;
  out[j * 5 + 4] = o4;
  out[N * 5 + j] = keep ? 1.0f : 0.0f;
}

// ---------------------------------------------------------------------------
extern "C" void kernel_launch(void* const* d_in, const int* in_sizes, int n_in,
                              void* d_out, int out_size, void* d_ws, size_t ws_size,
                              hipStream_t stream) {
  const float* boxes = (const float*)d_in[0];
  const float* scores = (const float*)d_in[1];
  const int* num_models = (const int*)d_in[2];
  float* out = (float*)d_out;

  char* p = (char*)d_ws;
  auto take = [&](size_t bytes) {
    char* r = p;
    p += (bytes + 255) & ~(size_t)255;
    return r;
  };
  u64* keys   = (u64*)take((size_t)N * 8);
  int* rank   = (int*)take((size_t)N * 4);
  float* bx1s = (float*)take((size_t)N * 4);
  float* by1s = (float*)take((size_t)N * 4);
  float* bx2s = (float*)take((size_t)N * 4);
  float* by2s = (float*)take((size_t)N * 4);
  float* ss   = (float*)take((size_t)N * 4);
  float* areas= (float*)take((size_t)N * 4);
  int* cluster= (int*)take((size_t)N * 4);
  int* cnt    = (int*)take((size_t)N * 4);
  float* prob = (float*)take((size_t)N * 4);
  unsigned* y2m = (unsigned*)take((size_t)N * 4);
  int* first  = (int*)take((size_t)N * 4);
  u64* mask   = (u64*)take((size_t)N * NWORDS * 8);  // 8 MiB

  k_init<<<N / 256, 256, 0, stream>>>(scores, keys, rank, cnt, prob, y2m, first);
  k_rank<<<dim3(N / 256, 8), 256, 0, stream>>>(keys, rank);
  k_scatter<<<N / 256, 256, 0, stream>>>(boxes, scores, rank, bx1s, by1s, bx2s, by2s, ss, areas);
  k_adj<<<dim3(N / 64, N / 64), 64, 0, stream>>>(bx1s, by1s, bx2s, by2s, areas, mask);
  k_scan<<<1, 64, 0, stream>>>((const ulong2*)mask, cluster);
  k_seg<<<N / 256, 256, 0, stream>>>(cluster, ss, by2s, cnt, prob, y2m);
  k_first<<<N / 256, 256, 0, stream>>>(cluster, by2s, y2m, first);
  k_out<<<N / 256, 256, 0, stream>>>(cluster, bx1s, by1s, bx2s, by2s, cnt, prob, first, num_models, out);
}

// Round 2
// 409.134 us; speedup vs baseline: 3.0914x; 3.0914x over previous
//
#include <hip/hip_runtime.h>
#include <cstdint>

#define N 8192
#define NWORDS 128   // 64-bit words per row
#define NGROUPS 256  // 32-row groups
typedef unsigned long long u64;
typedef unsigned int u32;

// ---------------------------------------------------------------------------
// K1: build sort keys (descending score, stable by ascending index) + init aux
// ---------------------------------------------------------------------------
__global__ __launch_bounds__(256) void k_init(const float* __restrict__ scores,
                                              u64* __restrict__ keys,
                                              int* __restrict__ rank,
                                              int* __restrict__ cnt,
                                              float* __restrict__ prob,
                                              unsigned* __restrict__ y2m,
                                              int* __restrict__ first) {
  int i = blockIdx.x * 256 + threadIdx.x;
  if (i >= N) return;
  float sc = scores[i];
  keys[i] = ((u64)__float_as_uint(sc) << 32) | (unsigned)(0xFFFFFFFFu - (unsigned)i);
  rank[i] = 0;
  cnt[i] = 0;
  prob[i] = 0.0f;
  y2m[i] = 0u;
  first[i] = N;
}

// ---------------------------------------------------------------------------
// K2: rank by counting (rank[i] = #{j : key[j] > key[i]}) -> stable descending
// ---------------------------------------------------------------------------
__global__ __launch_bounds__(256) void k_rank(const u64* __restrict__ keys,
                                              int* __restrict__ rank) {
  __shared__ u64 tile[1024];
  int e = blockIdx.x * 256 + threadIdx.x;
  int j0 = blockIdx.y * 1024;
  for (int t = threadIdx.x; t < 1024; t += 256) tile[t] = keys[j0 + t];
  __syncthreads();
  u64 ke = keys[e];
  int c = 0;
#pragma unroll 8
  for (int k = 0; k < 1024; ++k) c += (tile[k] > ke) ? 1 : 0;
  atomicAdd(&rank[e], c);
}

// ---------------------------------------------------------------------------
// K3: scatter into sorted SoA (clipped coords, score, area)
// ---------------------------------------------------------------------------
__global__ __launch_bounds__(256) void k_scatter(const float* __restrict__ boxes,
                                                 const float* __restrict__ scores,
                                                 const int* __restrict__ rank,
                                                 float* __restrict__ bx1s, float* __restrict__ by1s,
                                                 float* __restrict__ bx2s, float* __restrict__ by2s,
                                                 float* __restrict__ ss, float* __restrict__ areas) {
#pragma clang fp contract(off)
  int i = blockIdx.x * 256 + threadIdx.x;
  if (i >= N) return;
  int r = rank[i];
  float x1 = fminf(fmaxf(boxes[i * 4 + 0], 0.0f), 1920.0f);
  float y1 = fminf(fmaxf(boxes[i * 4 + 1], 0.0f), 1080.0f);
  float x2 = fminf(fmaxf(boxes[i * 4 + 2], 0.0f), 1920.0f);
  float y2 = fminf(fmaxf(boxes[i * 4 + 3], 0.0f), 1080.0f);
  bx1s[r] = x1; by1s[r] = y1; bx2s[r] = x2; by2s[r] = y2;
  ss[r] = scores[i];
  areas[r] = (x2 - x1 + 1.0f) * (y2 - y1 + 1.0f);
}

// ---------------------------------------------------------------------------
// K4: adjacency bitmask (64x64 tile per 64-thread block).
// fp contract OFF so iou matches the numpy reference bit-for-bit.
// NOTE: matrix is float-exact symmetric (min/max/add/mul all symmetric),
// which k_cluster relies on (column j == row j).
// ---------------------------------------------------------------------------
__global__ __launch_bounds__(64) void k_adj(const float* __restrict__ bx1s, const float* __restrict__ by1s,
                                            const float* __restrict__ bx2s, const float* __restrict__ by2s,
                                            const float* __restrict__ areas,
                                            u64* __restrict__ mask) {
#pragma clang fp contract(off)
  __shared__ float jx1[64], jy1[64], jx2[64], jy2[64], ja[64];
  int l = threadIdx.x;
  int j = blockIdx.x * 64 + l;
  jx1[l] = bx1s[j]; jy1[l] = by1s[j]; jx2[l] = bx2s[j]; jy2[l] = by2s[j]; ja[l] = areas[j];
  __syncthreads();
  int i = blockIdx.y * 64 + l;
  float x1 = bx1s[i], y1 = by1s[i], x2 = bx2s[i], y2 = by2s[i], ai = areas[i];
  u64 bits = 0;
#pragma unroll 4
  for (int jj = 0; jj < 64; ++jj) {
    float ix1 = fmaxf(x1, jx1[jj]);
    float iy1 = fmaxf(y1, jy1[jj]);
    float ix2 = fminf(x2, jx2[jj]);
    float iy2 = fminf(y2, jy2[jj]);
    float iw = fmaxf(ix2 - ix1 + 1.0f, 0.0f);
    float ih = fmaxf(iy2 - iy1 + 1.0f, 0.0f);
    float inter = iw * ih;
    float uni = (ai + ja[jj]) - inter;
    float iou = inter / uni;
    bits |= ((u64)(iou > 0.5f)) << jj;
  }
  mask[(size_t)i * NWORDS + blockIdx.x] = bits;
}

// ---------------------------------------------------------------------------
// K5: head-set discovery. ONE wave, wave-synchronous, serial over 32-row
// groups. Lane l holds removed words 2l,2l+1 (cols [128l,128l+128)).
// Per-group removed bits + per-head diagonal words fetched via v_readlane
// (scalar chain), rows double-buffered in VGPRs (A/B, 32 rows each).
// Output: headw[g] = 32-bit head bitmap for rows [32g,32g+32).
// Claims/cluster assignment are done by the parallel k_cluster afterwards:
// cluster[j] = min{h in Heads : adj[h][j]}  (exact greedy semantics).
// ---------------------------------------------------------------------------
__global__ __launch_bounds__(64, 1) void k_scan(const ulong2* __restrict__ mask2,
                                                u32* __restrict__ headw) {
  const int l = threadIdx.x;
  u64 remv0 = 0, remv1 = 0;
  ulong2 A[32], B[32];

  auto process32 = [&](ulong2 (&R)[32], int g) {
    const int gl = g >> 2;            // lane owning word w = g>>1
    const int comp = (g >> 1) & 1;    // which remv/word component
    const int halfsh = (g & 1) * 32;  // which half of the word
    u64 rmw = comp ? remv1 : remv0;
    u32 rm32 = (u32)(rmw >> halfsh);
    u32 todo = ~(u32)__builtin_amdgcn_readlane((int)rm32, gl);
    u32 hm = 0;
#pragma unroll
    for (int i = 0; i < 32; ++i) {
      if (todo & (1u << i)) {  // row 32g+i is a head
        u64 dv = comp ? R[i].y : R[i].x;      // this lane's copy of row's word w
        u32 dh = (u32)(dv >> halfsh);
        u32 diag = (u32)__builtin_amdgcn_readlane((int)dh, gl);
        todo &= ~diag;                         // rows claimed in-group (incl. i)
        hm |= (1u << i);
        remv0 |= R[i].x;                       // full-row claim, all columns
        remv1 |= R[i].y;
      }
    }
    if (l == 0) headw[g] = hm;
  };

  // prefetch group 0 into A
#pragma unroll
  for (int i = 0; i < 32; ++i) A[i] = mask2[(size_t)i * 64 + l];

  for (int g = 0; g < NGROUPS; g += 2) {
#pragma unroll
    for (int i = 0; i < 32; ++i) B[i] = mask2[(size_t)((g + 1) * 32 + i) * 64 + l];
    process32(A, g);
    if (g + 2 < NGROUPS) {
#pragma unroll
      for (int i = 0; i < 32; ++i) A[i] = mask2[(size_t)((g + 2) * 32 + i) * 64 + l];
    }
    process32(B, g + 1);
  }
}

// ---------------------------------------------------------------------------
// K6: parallel cluster assignment + segment atomics (fused).
// One wave per row j: cluster[j] = first set bit of (row_j & headmask).
// Uses symmetry: column j of adj == row j.
// ---------------------------------------------------------------------------
__global__ __launch_bounds__(256) void k_cluster(const ulong2* __restrict__ mask2,
                                                 const u32* __restrict__ headw,
                                                 const float* __restrict__ ss,
                                                 const float* __restrict__ by2s,
                                                 int* __restrict__ cluster,
                                                 int* __restrict__ cnt,
                                                 float* __restrict__ prob,
                                                 unsigned* __restrict__ y2m) {
  int l = threadIdx.x & 63;
  int wv = threadIdx.x >> 6;
  int j = blockIdx.x * 4 + wv;
  ulong2 r = mask2[(size_t)j * 64 + l];
  // lane l holds head-bitmap words 2l, 2l+1 (groups 4l..4l+3)
  u64 hm0 = (u64)headw[4 * l + 0] | ((u64)headw[4 * l + 1] << 32);
  u64 hm1 = (u64)headw[4 * l + 2] | ((u64)headw[4 * l + 3] << 32);
  u64 v0 = r.x & hm0;
  u64 v1 = r.y & hm1;
  bool has = (v0 | v1) != 0ull;
  int local = v0 ? __builtin_ctzll(v0) : (v1 ? 64 + __builtin_ctzll(v1) : 0);
  int pos = l * 128 + local;
  u64 b = __ballot(has);
  int firstlane = __builtin_ctzll(b);  // guaranteed: j adjacent to >=1 head
  int c = __shfl(pos, firstlane);
  if (l == 0) {
    cluster[j] = c;
    atomicAdd(&cnt[c], 1);
    atomicAdd(&prob[c], ss[j]);
    atomicMax(&y2m[c], __float_as_uint(by2s[j]));
  }
}

// ---------------------------------------------------------------------------
// K7: first index achieving the cluster max y2
// ---------------------------------------------------------------------------
__global__ __launch_bounds__(256) void k_first(const int* __restrict__ cluster,
                                               const float* __restrict__ by2s,
                                               const unsigned* __restrict__ y2m,
                                               int* __restrict__ first) {
  int j = blockIdx.x * 256 + threadIdx.x;
  if (j >= N) return;
  int c = cluster[j];
  if (by2s[j] >= __uint_as_float(y2m[c])) atomicMin(&first[c], j);
}

// ---------------------------------------------------------------------------
// K8: outputs. out[j][0..4] then keep[j] appended (floats 0/1).
// ---------------------------------------------------------------------------
__global__ __launch_bounds__(256) void k_out(const int* __restrict__ cluster,
                                             const float* __restrict__ bx1s, const float* __restrict__ by1s,
                                             const float* __restrict__ bx2s, const float* __restrict__ by2s,
                                             const int* __restrict__ cnt,
                                             const float* __restrict__ prob,
                                             const int* __restrict__ first,
                                             const int* __restrict__ num_models,
                                             float* __restrict__ out) {
  int j = blockIdx.x * 256 + threadIdx.x;
  if (j >= N) return;
  int c = cluster[j];
  int nm = num_models[0];
  bool valid = (float)cnt[c] >= (float)nm / 3.0f;
  bool pick = (first[c] == j);
  bool keep = pick && valid;
  float o0 = 0.f, o1 = 0.f, o2 = 0.f, o3 = 0.f, o4 = 0.f;
  if (keep) {
    o0 = bx1s[j]; o1 = by1s[j]; o2 = bx2s[j]; o3 = by2s[j];
    o4 = prob[c] / (float)nm;
  }
  out[j * 5 + 0] = o0;
  out[j * 5 + 1] = o1;
  out[j * 5 + 2] = o2;
  out[j * 5 + 3] = o3;
  out[j * 5 + 4] = o4;
  out[N * 5 + j] = keep ? 1.0f : 0.0f;
}

// ---------------------------------------------------------------------------
extern "C" void kernel_launch(void* const* d_in, const int* in_sizes, int n_in,
                              void* d_out, int out_size, void* d_ws, size_t ws_size,
                              hipStream_t stream) {
  const float* boxes = (const float*)d_in[0];
  const float* scores = (const float*)d_in[1];
  const int* num_models = (const int*)d_in[2];
  float* out = (float*)d_out;

  char* p = (char*)d_ws;
  auto take = [&](size_t bytes) {
    char* r = p;
    p += (bytes + 255) & ~(size_t)255;
    return r;
  };
  u64* keys   = (u64*)take((size_t)N * 8);
  int* rank   = (int*)take((size_t)N * 4);
  float* bx1s = (float*)take((size_t)N * 4);
  float* by1s = (float*)take((size_t)N * 4);
  float* bx2s = (float*)take((size_t)N * 4);
  float* by2s = (float*)take((size_t)N * 4);
  float* ss   = (float*)take((size_t)N * 4);
  float* areas= (float*)take((size_t)N * 4);
  int* cluster= (int*)take((size_t)N * 4);
  int* cnt    = (int*)take((size_t)N * 4);
  float* prob = (float*)take((size_t)N * 4);
  unsigned* y2m = (unsigned*)take((size_t)N * 4);
  int* first  = (int*)take((size_t)N * 4);
  u32* headw  = (u32*)take((size_t)NGROUPS * 4);
  u64* mask   = (u64*)take((size_t)N * NWORDS * 8);  // 8 MiB

  k_init<<<N / 256, 256, 0, stream>>>(scores, keys, rank, cnt, prob, y2m, first);
  k_rank<<<dim3(N / 256, 8), 256, 0, stream>>>(keys, rank);
  k_scatter<<<N / 256, 256, 0, stream>>>(boxes, scores, rank, bx1s, by1s, bx2s, by2s, ss, areas);
  k_adj<<<dim3(N / 64, N / 64), 64, 0, stream>>>(bx1s, by1s, bx2s, by2s, areas, mask);
  k_scan<<<1, 64, 0, stream>>>((const ulong2*)mask, headw);
  k_cluster<<<N / 4, 256, 0, stream>>>((const ulong2*)mask, headw, ss, by2s, cluster, cnt, prob, y2m);
  k_first<<<N / 256, 256, 0, stream>>>(cluster, by2s, y2m, first);
  k_out<<<N / 256, 256, 0, stream>>>(cluster, bx1s, by1s, bx2s, by2s, cnt, prob, first, num_models, out);
}